// Round 7
// baseline (734.839 us; speedup 1.0000x reference)
//
#include <hip/hip_runtime.h>

#define BLOCK 256
#define NB 5      // objects per scene
#define DD 12     // per-object feature dim
#define EE 64     // goal embedding dim
#define HH 32     // F1 hidden dim
#define ROW 81    // D + E + N
#define OUTW 405  // N * ROW
#define TILE 64   // rows per block in assemble kernel
#define BPB 128   // batches per block in zhat kernel (2 threads/batch, cross-wave pair)

// ---------------- kernel A: compute zhat[B,5], 2 threads per batch ----------------
// Waves 2w,2w+1 cover the same 64 batches (lane -> batch); wave parity picks the
// 16-hidden-unit half => h is wave-uniform => W1/W2/b1 via scalar loads.
__global__ __launch_bounds__(BLOCK, 4) void zhat_kernel(
    const float* __restrict__ obs, const float* __restrict__ ghat,
    const float* __restrict__ W1, const float* __restrict__ b1,
    const float* __restrict__ W2, const float* __restrict__ b2,
    float* __restrict__ zbuf, int zstride, int zoff, int B)
{
    __shared__ float s_u[25 * BLOCK];  // union: g2 scratch (tid*17+hp) / exchange [q][tid]
    __shared__ float s_w2s[HH];        // rowsum(W2)
    __shared__ float s_sb2;            // sum(b2)

    const int tid  = threadIdx.x;
    const int lane = tid & 63;
    const int wv   = __builtin_amdgcn_readfirstlane(tid >> 6);
    const int g    = wv & 1;                      // h-half selector (wave-uniform)
    const int slot = (wv >> 1) * 64 + lane;       // batch slot 0..127
    int i = blockIdx.x * BPB + slot;
    const bool valid = (i < B);
    if (!valid) i = (B > 0) ? B - 1 : 0;          // clamp loads; stores guarded

    // ---- batch-independent scalars ----
    if (tid < HH) {
        float s = 0.f;
        const float4* p = reinterpret_cast<const float4*>(W2 + tid * EE);
        #pragma unroll
        for (int q = 0; q < EE / 4; ++q) { float4 v = p[q]; s += (v.x + v.y) + (v.z + v.w); }
        s_w2s[tid] = s;
    } else if (tid == HH) {
        float s = 0.f;
        #pragma unroll
        for (int e = 0; e < EE; ++e) s += b2[e];
        s_sb2 = s;
    }

    // ---- obs row (60 floats) into registers (issued early for latency overlap) ----
    float o[NB * DD];
    {
        const float4* p = reinterpret_cast<const float4*>(obs + (size_t)i * (NB * DD));
        #pragma unroll
        for (int q = 0; q < NB * DD / 4; ++q) {
            float4 v = p[q];
            o[4*q+0] = v.x; o[4*q+1] = v.y; o[4*q+2] = v.z; o[4*q+3] = v.w;
        }
    }

    // ---- GEMV: g2[hp] = W2[g*16+hp, :] . ghat_i   (16 indep accumulators) ----
    float g2[16];
    #pragma unroll
    for (int hp = 0; hp < 16; ++hp) g2[hp] = 0.f;
    {
        const float* grow = ghat + (size_t)i * EE;
        for (int ec = 0; ec < 4; ++ec) {          // runtime loop: short gc live range
            float gc[16];
            const float4* gp = reinterpret_cast<const float4*>(grow + ec * 16);
            #pragma unroll
            for (int q = 0; q < 4; ++q) {
                float4 v = gp[q];
                gc[4*q+0] = v.x; gc[4*q+1] = v.y; gc[4*q+2] = v.z; gc[4*q+3] = v.w;
            }
            const float* w2b = W2 + (size_t)(g * 16) * EE + ec * 16;  // SGPR base
            #pragma unroll
            for (int q = 0; q < 16; ++q) {
                #pragma unroll
                for (int hp = 0; hp < 16; ++hp)
                    g2[hp] += gc[q] * w2b[hp * EE + q];   // wave-uniform -> s_load
            }
        }
    }
    #pragma unroll
    for (int hp = 0; hp < 16; ++hp) s_u[tid * 17 + hp] = g2[hp];  // stride 17: conflict-free
    __syncthreads();   // b1: publishes s_u(g2) / s_w2s / s_sb2

    // ---- pass 1: partial logits + hw over my 16 hidden units ----
    float w[NB * NB], hw[NB * NB];
    #pragma unroll
    for (int q = 0; q < NB * NB; ++q) { w[q] = 0.f; hw[q] = 0.f; }

    for (int c = 0; c < 2; ++c) {                 // runtime chunk loop (8 h per chunk)
        const int hb = g * 16 + c * 8;            // wave-uniform
        #pragma unroll
        for (int hp = 0; hp < 8; ++hp) {
            const int h = hb + hp;                // wave-uniform -> scalar W1/b1 loads
            const float g2v = s_u[tid * 17 + c * 8 + hp];
            const float w2v = s_w2s[h];
            float a[NB], bb[NB];
            const float b1h = b1[h];
            #pragma unroll
            for (int j = 0; j < NB; ++j) { a[j] = b1h; bb[j] = 0.f; }
            #pragma unroll
            for (int d = 0; d < DD; ++d) {        // d outer, j inner: 10 indep accs
                const float w1t = W1[d * HH + h];
                const float w1b = W1[(DD + d) * HH + h];
                #pragma unroll
                for (int j = 0; j < NB; ++j) {
                    a[j]  += o[j*DD + d] * w1t;
                    bb[j] += o[j*DD + d] * w1b;
                }
            }
            #pragma unroll
            for (int j = 0; j < NB; ++j) {
                #pragma unroll
                for (int k = 0; k < NB; ++k) {
                    const float hv = fmaxf(a[j] + bb[k], 0.f);
                    w[j*NB + k]  += hv * g2v;
                    hw[j*NB + k] += hv * w2v;
                }
            }
        }
    }
    __syncthreads();   // b2: all g2 reads done; s_u free for exchange

    // ---- exchange logit partials with cross-wave partner (tid ^ 64) ----
    #pragma unroll
    for (int q = 0; q < NB * NB; ++q) s_u[q * BLOCK + tid] = w[q];
    __syncthreads();   // b3
    #pragma unroll
    for (int q = 0; q < NB * NB; ++q) w[q] += s_u[q * BLOCK + (tid ^ 64)];

    // ---- softmax over 25 pairs (redundant in both partners; identical) ----
    float m = w[0];
    #pragma unroll
    for (int q = 1; q < NB * NB; ++q) m = fmaxf(m, w[q]);
    #pragma unroll
    for (int q = 0; q < NB * NB; ++q) w[q] = __expf(w[q] - m);   // w := unnorm p
    float racc[NB];
    float l = 0.f;
    #pragma unroll
    for (int j = 0; j < NB; ++j) {
        float r = 0.f;
        #pragma unroll
        for (int k = 0; k < NB; ++k) r += w[j*NB + k];
        racc[j] = r; l += r;
    }

    // ---- partial zacc over my h-half: zacc[j] = sum_k p[jk]*hw[jk] ----
    float zacc[NB];
    #pragma unroll
    for (int j = 0; j < NB; ++j) {
        float z = 0.f;
        #pragma unroll
        for (int k = 0; k < NB; ++k) z += w[j*NB + k] * hw[j*NB + k];
        zacc[j] = z;
    }

    __syncthreads();   // b4: partner's exchange reads done; reuse rows 0..4
    #pragma unroll
    for (int j = 0; j < NB; ++j) s_u[j * BLOCK + tid] = zacc[j];
    __syncthreads();   // b5
    if (valid && g == 0) {
        const float invl = 1.f / l;
        const float sb2 = s_sb2;
        float* zr = zbuf + (size_t)i * zstride + zoff;
        #pragma unroll
        for (int j = 0; j < NB; ++j) {
            const float zt = zacc[j] + s_u[j * BLOCK + (tid ^ 64)];
            zr[j] = (zt + sb2 * racc[j]) * invl;
        }
    }
}

// ---------------- kernel B: assemble output (proven R3 path) ----------------
__global__ __launch_bounds__(BLOCK) void assemble_kernel(
    const float* __restrict__ obs, const float* __restrict__ ghat,
    const float* __restrict__ zbuf, int zstride, int zoff,
    float* __restrict__ out, int B)
{
    __shared__ float s_obs[TILE * NB * DD];  // 3840 floats
    __shared__ float s_gh[TILE * EE];        // 4096 floats
    __shared__ float s_zh[TILE * NB];        // 320 floats

    const int tid = threadIdx.x;
    const int r0 = blockIdx.x * TILE;
    const int rows = (B - r0 < TILE) ? (B - r0) : TILE;

    for (int t = tid; t < rows * NB * DD; t += BLOCK)
        s_obs[t] = obs[(size_t)r0 * NB * DD + t];
    for (int t = tid; t < rows * EE; t += BLOCK)
        s_gh[t] = ghat[(size_t)r0 * EE + t];
    for (int t = tid; t < rows * NB; t += BLOCK) {
        const int row = t / NB, k = t - row * NB;
        s_zh[t] = zbuf[(size_t)(r0 + row) * zstride + zoff + k];
    }
    __syncthreads();

    const size_t base = (size_t)r0 * OUTW;
    for (int t = tid; t < rows * OUTW; t += BLOCK) {
        const int il = t / OUTW;
        const int r  = t - il * OUTW;
        const int j  = r / ROW;
        const int rr = r - j * ROW;
        float v;
        if (rr < DD)           v = s_obs[il * NB * DD + j * DD + rr];
        else if (rr < DD + EE) v = s_gh[il * EE + (rr - DD)];
        else                   v = s_zh[il * NB + (rr - (DD + EE))];
        out[base + t] = v;
    }
}

extern "C" void kernel_launch(void* const* d_in, const int* in_sizes, int n_in,
                              void* d_out, int out_size, void* d_ws, size_t ws_size,
                              hipStream_t stream) {
    const float* obs  = (const float*)d_in[0];
    const float* ghat = (const float*)d_in[1];
    const float* W1   = (const float*)d_in[2];
    const float* b1   = (const float*)d_in[3];
    const float* W2   = (const float*)d_in[4];
    const float* b2   = (const float*)d_in[5];
    float* out = (float*)d_out;

    const int B = in_sizes[0] / (NB * DD);

    // zhat scratch: d_ws if large enough, else stash in last 5 floats of each
    // output row (assemble reads its tile's stash before overwriting it).
    float* zbuf; int zstride, zoff;
    if (ws_size >= (size_t)B * NB * sizeof(float)) {
        zbuf = (float*)d_ws; zstride = NB;   zoff = 0;
    } else {
        zbuf = out;          zstride = OUTW; zoff = OUTW - NB;
    }

    const int gridA = (B + BPB - 1) / BPB;
    hipLaunchKernelGGL(zhat_kernel, dim3(gridA), dim3(BLOCK), 0, stream,
                       obs, ghat, W1, b1, W2, b2, zbuf, zstride, zoff, B);

    const int gridB = (B + TILE - 1) / TILE;
    hipLaunchKernelGGL(assemble_kernel, dim3(gridB), dim3(BLOCK), 0, stream,
                       obs, ghat, zbuf, zstride, zoff, out, B);
}

// Round 8
// 318.005 us; speedup vs baseline: 2.3108x; 2.3108x over previous
//
#include <hip/hip_runtime.h>

#define BLOCK 256
#define NB 5      // objects per scene
#define DD 12     // per-object feature dim
#define EE 64     // goal embedding dim
#define HH 32     // F1 hidden dim
#define ROW 81    // D + E + N
#define OUTW 405  // N * ROW
#define TILE 64   // rows per block in assemble kernel
#define BPB 128   // batches per block in zhat kernel (2 threads/batch, cross-wave pair)

// ---------------- kernel A: compute zhat[B,5], 2 threads per batch ----------------
// Waves 2w,2w+1 cover the same 64 batches (lane -> batch); wave parity picks the
// 16-hidden-unit half => h is wave-uniform => W1/W2/b1 via scalar loads.
// Logits-only pass 1 (no hw accumulator), exchange, softmax redundantly, then
// pass 2 recomputes hv and contracts with rowsum(W2). Keeps state < 128 VGPR.
__global__ __launch_bounds__(BLOCK, 2) void zhat_kernel(
    const float* __restrict__ obs, const float* __restrict__ ghat,
    const float* __restrict__ W1, const float* __restrict__ b1,
    const float* __restrict__ W2, const float* __restrict__ b2,
    float* __restrict__ zbuf, int zstride, int zoff, int B)
{
    __shared__ float s_u[25 * BLOCK];  // union: g2 scratch (tid*17+hp) / exchange [q][tid]
    __shared__ float s_w2s[HH];        // rowsum(W2)
    __shared__ float s_sb2;            // sum(b2)

    const int tid  = threadIdx.x;
    const int lane = tid & 63;
    const int wv   = __builtin_amdgcn_readfirstlane(tid >> 6);
    const int g    = wv & 1;                      // h-half selector (wave-uniform)
    const int slot = (wv >> 1) * 64 + lane;       // batch slot 0..127
    int i = blockIdx.x * BPB + slot;
    const bool valid = (i < B);
    if (!valid) i = (B > 0) ? B - 1 : 0;          // clamp loads; stores guarded

    // ---- batch-independent scalars ----
    if (tid < HH) {
        float s = 0.f;
        const float4* p = reinterpret_cast<const float4*>(W2 + tid * EE);
        #pragma unroll
        for (int q = 0; q < EE / 4; ++q) { float4 v = p[q]; s += (v.x + v.y) + (v.z + v.w); }
        s_w2s[tid] = s;
    } else if (tid == HH) {
        float s = 0.f;
        #pragma unroll
        for (int e = 0; e < EE; ++e) s += b2[e];
        s_sb2 = s;
    }

    // ---- obs row (60 floats) into registers ----
    float o[NB * DD];
    {
        const float4* p = reinterpret_cast<const float4*>(obs + (size_t)i * (NB * DD));
        #pragma unroll
        for (int q = 0; q < NB * DD / 4; ++q) {
            float4 v = p[q];
            o[4*q+0] = v.x; o[4*q+1] = v.y; o[4*q+2] = v.z; o[4*q+3] = v.w;
        }
    }

    // ---- GEMV: g2[hp] = W2[g*16+hp, :] . ghat_i   (16 indep accumulators) ----
    {
        float g2[16];
        #pragma unroll
        for (int hp = 0; hp < 16; ++hp) g2[hp] = 0.f;
        const float* grow = ghat + (size_t)i * EE;
        #pragma unroll 1
        for (int ec = 0; ec < 4; ++ec) {
            float gc[16];
            const float4* gp = reinterpret_cast<const float4*>(grow + ec * 16);
            #pragma unroll
            for (int q = 0; q < 4; ++q) {
                float4 v = gp[q];
                gc[4*q+0] = v.x; gc[4*q+1] = v.y; gc[4*q+2] = v.z; gc[4*q+3] = v.w;
            }
            const float* w2b = W2 + (size_t)(g * 16) * EE + ec * 16;  // wave-uniform base
            #pragma unroll
            for (int q = 0; q < 16; ++q) {
                #pragma unroll
                for (int hp = 0; hp < 16; ++hp)
                    g2[hp] += gc[q] * w2b[hp * EE + q];   // s_load weights
            }
        }
        #pragma unroll
        for (int hp = 0; hp < 16; ++hp) s_u[tid * 17 + hp] = g2[hp];  // stride 17
    }
    __syncthreads();   // b1: publishes s_u(g2) / s_w2s / s_sb2

    // ---- pass 1: partial logits over my 16 hidden units (logits ONLY) ----
    float w[NB * NB];
    #pragma unroll
    for (int q = 0; q < NB * NB; ++q) w[q] = 0.f;

    #pragma unroll 1
    for (int c = 0; c < 2; ++c) {
        const int hb = g * 16 + c * 8;            // wave-uniform
        #pragma unroll
        for (int hp = 0; hp < 8; ++hp) {
            const int h = hb + hp;                // wave-uniform -> scalar W1/b1 loads
            const float g2v = s_u[tid * 17 + c * 8 + hp];
            float a[NB], bb[NB];
            const float b1h = b1[h];
            #pragma unroll
            for (int j = 0; j < NB; ++j) { a[j] = b1h; bb[j] = 0.f; }
            #pragma unroll
            for (int d = 0; d < DD; ++d) {        // d outer, j inner: 10 indep accs
                const float w1t = W1[d * HH + h];
                const float w1b = W1[(DD + d) * HH + h];
                #pragma unroll
                for (int j = 0; j < NB; ++j) {
                    a[j]  += o[j*DD + d] * w1t;
                    bb[j] += o[j*DD + d] * w1b;
                }
            }
            #pragma unroll
            for (int j = 0; j < NB; ++j)
                #pragma unroll
                for (int k = 0; k < NB; ++k)
                    w[j*NB + k] += fmaxf(a[j] + bb[k], 0.f) * g2v;
        }
    }
    __syncthreads();   // b2: all g2 reads done; s_u free for exchange

    // ---- exchange logit partials with cross-wave partner (tid ^ 64) ----
    #pragma unroll
    for (int q = 0; q < NB * NB; ++q) s_u[q * BLOCK + tid] = w[q];
    __syncthreads();   // b3
    #pragma unroll
    for (int q = 0; q < NB * NB; ++q) w[q] += s_u[q * BLOCK + (tid ^ 64)];

    // ---- softmax over 25 pairs (redundant in both partners; identical) ----
    float m = w[0];
    #pragma unroll
    for (int q = 1; q < NB * NB; ++q) m = fmaxf(m, w[q]);
    #pragma unroll
    for (int q = 0; q < NB * NB; ++q) w[q] = __expf(w[q] - m);   // w := unnorm p
    float racc[NB];
    float l = 0.f;
    #pragma unroll
    for (int j = 0; j < NB; ++j) {
        float r = 0.f;
        #pragma unroll
        for (int k = 0; k < NB; ++k) r += w[j*NB + k];
        racc[j] = r; l += r;
    }

    // ---- pass 2: recompute hv over my 16 h; zacc[j] += w2s[h] * sum_k p*hv ----
    float zacc[NB];
    #pragma unroll
    for (int j = 0; j < NB; ++j) zacc[j] = 0.f;

    #pragma unroll 1
    for (int c = 0; c < 2; ++c) {
        const int hb = g * 16 + c * 8;
        #pragma unroll
        for (int hp = 0; hp < 8; ++hp) {
            const int h = hb + hp;
            const float w2v = s_w2s[h];           // uniform LDS addr -> broadcast
            float a[NB], bb[NB];
            const float b1h = b1[h];
            #pragma unroll
            for (int j = 0; j < NB; ++j) { a[j] = b1h; bb[j] = 0.f; }
            #pragma unroll
            for (int d = 0; d < DD; ++d) {
                const float w1t = W1[d * HH + h];
                const float w1b = W1[(DD + d) * HH + h];
                #pragma unroll
                for (int j = 0; j < NB; ++j) {
                    a[j]  += o[j*DD + d] * w1t;
                    bb[j] += o[j*DD + d] * w1b;
                }
            }
            #pragma unroll
            for (int j = 0; j < NB; ++j) {
                float t = 0.f;
                #pragma unroll
                for (int k = 0; k < NB; ++k)
                    t += w[j*NB + k] * fmaxf(a[j] + bb[k], 0.f);
                zacc[j] += w2v * t;
            }
        }
    }

    __syncthreads();   // b4: partner's exchange reads done; reuse rows 0..4
    #pragma unroll
    for (int j = 0; j < NB; ++j) s_u[j * BLOCK + tid] = zacc[j];
    __syncthreads();   // b5
    if (valid && g == 0) {
        const float invl = 1.f / l;
        const float sb2 = s_sb2;
        float* zr = zbuf + (size_t)i * zstride + zoff;
        #pragma unroll
        for (int j = 0; j < NB; ++j) {
            const float zt = zacc[j] + s_u[j * BLOCK + (tid ^ 64)];
            zr[j] = (zt + sb2 * racc[j]) * invl;
        }
    }
}

// ---------------- kernel B: assemble output (proven R3 path) ----------------
__global__ __launch_bounds__(BLOCK) void assemble_kernel(
    const float* __restrict__ obs, const float* __restrict__ ghat,
    const float* __restrict__ zbuf, int zstride, int zoff,
    float* __restrict__ out, int B)
{
    __shared__ float s_obs[TILE * NB * DD];  // 3840 floats
    __shared__ float s_gh[TILE * EE];        // 4096 floats
    __shared__ float s_zh[TILE * NB];        // 320 floats

    const int tid = threadIdx.x;
    const int r0 = blockIdx.x * TILE;
    const int rows = (B - r0 < TILE) ? (B - r0) : TILE;

    for (int t = tid; t < rows * NB * DD; t += BLOCK)
        s_obs[t] = obs[(size_t)r0 * NB * DD + t];
    for (int t = tid; t < rows * EE; t += BLOCK)
        s_gh[t] = ghat[(size_t)r0 * EE + t];
    for (int t = tid; t < rows * NB; t += BLOCK) {
        const int row = t / NB, k = t - row * NB;
        s_zh[t] = zbuf[(size_t)(r0 + row) * zstride + zoff + k];
    }
    __syncthreads();

    const size_t base = (size_t)r0 * OUTW;
    for (int t = tid; t < rows * OUTW; t += BLOCK) {
        const int il = t / OUTW;
        const int r  = t - il * OUTW;
        const int j  = r / ROW;
        const int rr = r - j * ROW;
        float v;
        if (rr < DD)           v = s_obs[il * NB * DD + j * DD + rr];
        else if (rr < DD + EE) v = s_gh[il * EE + (rr - DD)];
        else                   v = s_zh[il * NB + (rr - (DD + EE))];
        out[base + t] = v;
    }
}

extern "C" void kernel_launch(void* const* d_in, const int* in_sizes, int n_in,
                              void* d_out, int out_size, void* d_ws, size_t ws_size,
                              hipStream_t stream) {
    const float* obs  = (const float*)d_in[0];
    const float* ghat = (const float*)d_in[1];
    const float* W1   = (const float*)d_in[2];
    const float* b1   = (const float*)d_in[3];
    const float* W2   = (const float*)d_in[4];
    const float* b2   = (const float*)d_in[5];
    float* out = (float*)d_out;

    const int B = in_sizes[0] / (NB * DD);

    // zhat scratch: d_ws if large enough, else stash in last 5 floats of each
    // output row (assemble reads its tile's stash before overwriting it).
    float* zbuf; int zstride, zoff;
    if (ws_size >= (size_t)B * NB * sizeof(float)) {
        zbuf = (float*)d_ws; zstride = NB;   zoff = 0;
    } else {
        zbuf = out;          zstride = OUTW; zoff = OUTW - NB;
    }

    const int gridA = (B + BPB - 1) / BPB;
    hipLaunchKernelGGL(zhat_kernel, dim3(gridA), dim3(BLOCK), 0, stream,
                       obs, ghat, W1, b1, W2, b2, zbuf, zstride, zoff, B);

    const int gridB = (B + TILE - 1) / TILE;
    hipLaunchKernelGGL(assemble_kernel, dim3(gridB), dim3(BLOCK), 0, stream,
                       obs, ghat, zbuf, zstride, zoff, out, B);
}

// Round 9
// 145.196 us; speedup vs baseline: 5.0610x; 2.1902x over previous
//
#include <hip/hip_runtime.h>

#define BLOCK 256
#define NB 5      // objects per scene
#define DD 12     // per-object feature dim
#define EE 64     // goal embedding dim
#define HH 32     // F1 hidden dim
#define ROW 81    // D + E + N
#define OUTW 405  // N * ROW
#define TILE 64   // rows per block in assemble kernel
#define BPB 128   // batches per block in zhat kernel (2 threads/batch, within-wave pair)
#define W1P 28    // padded W1^T row stride (16B-aligned float4 reads)

// ---------------- kernel A: compute zhat[B,5], 2 threads per batch ----------------
// Lanes 2m/2m+1 share batch; lane parity picks the 16-hidden-unit half.
// Single pass accumulates w (logits) and hw; partials combined via shfl_xor(1).
// W1^T/b1/w2s in LDS (broadcast reads); W2 GEMV via wave-uniform s_loads.
__global__ __launch_bounds__(BLOCK) void zhat_kernel(
    const float* __restrict__ obs, const float* __restrict__ ghat,
    const float* __restrict__ W1, const float* __restrict__ b1,
    const float* __restrict__ W2, const float* __restrict__ b2,
    float* __restrict__ zbuf, int zstride, int zoff, int B)
{
    __shared__ float s_W1t[HH * W1P];     // W1^T: [h][d], d<24, padded to 28
    __shared__ float s_b1[HH];
    __shared__ float s_w2s[HH];           // rowsum(W2)
    __shared__ float s_sb2;               // sum(b2)
    __shared__ float s_g2[BLOCK * 17];    // per-thread g2 half (stride 17: 2-way max)

    const int tid = threadIdx.x;

    // ---- stage W1^T, b1, w2s, sb2 (one wave) ----
    if (tid < HH) {
        #pragma unroll
        for (int d = 0; d < 2 * DD; ++d)
            s_W1t[tid * W1P + d] = W1[d * HH + tid];
        s_b1[tid] = b1[tid];
        float s = 0.f;
        const float4* p = reinterpret_cast<const float4*>(W2 + tid * EE);
        #pragma unroll
        for (int q = 0; q < EE / 4; ++q) { float4 v = p[q]; s += (v.x + v.y) + (v.z + v.w); }
        s_w2s[tid] = s;
    } else if (tid == HH) {
        float s = 0.f;
        #pragma unroll
        for (int e = 0; e < EE; ++e) s += b2[e];
        s_sb2 = s;
    }

    const int lane = tid & 63;
    const int par  = lane & 1;                        // h-half selector (per-lane)
    const int slot = (tid >> 6) * 32 + (lane >> 1);   // batch slot 0..127
    int i = blockIdx.x * BPB + slot;
    const bool valid = (i < B);
    if (!valid) i = (B > 0) ? B - 1 : 0;              // clamp loads; store guarded

    // ---- obs row (60 floats) into registers ----
    float o[NB * DD];
    {
        const float4* p = reinterpret_cast<const float4*>(obs + (size_t)i * (NB * DD));
        #pragma unroll
        for (int q = 0; q < NB * DD / 4; ++q) {
            float4 v = p[q];
            o[4*q+0] = v.x; o[4*q+1] = v.y; o[4*q+2] = v.z; o[4*q+3] = v.w;
        }
    }

    // ---- GEMV: g2[h] = W2[h,:] . ghat_i for ALL 32 h (W2 via uniform s_load);
    //      park my parity's 16 in LDS scratch ----
    {
        float g2[HH];
        #pragma unroll
        for (int h = 0; h < HH; ++h) g2[h] = 0.f;
        const float* grow = ghat + (size_t)i * EE;
        #pragma unroll 1
        for (int ec = 0; ec < 8; ++ec) {              // 8 e per chunk, runtime loop
            float gc[8];
            const float4* gp = reinterpret_cast<const float4*>(grow + ec * 8);
            float4 v0 = gp[0], v1 = gp[1];
            gc[0]=v0.x; gc[1]=v0.y; gc[2]=v0.z; gc[3]=v0.w;
            gc[4]=v1.x; gc[5]=v1.y; gc[6]=v1.z; gc[7]=v1.w;
            #pragma unroll
            for (int q = 0; q < 8; ++q) {
                #pragma unroll
                for (int h = 0; h < HH; ++h)
                    g2[h] += gc[q] * W2[h * EE + ec * 8 + q];   // wave-uniform -> s_load
            }
        }
        if (par == 0) {
            #pragma unroll
            for (int hp = 0; hp < 16; ++hp) s_g2[tid * 17 + hp] = g2[hp];
        } else {
            #pragma unroll
            for (int hp = 0; hp < 16; ++hp) s_g2[tid * 17 + hp] = g2[16 + hp];
        }
    }
    __syncthreads();   // publishes s_W1t / s_b1 / s_w2s / s_sb2 (s_g2 is own-slot)

    // ---- single pass: partial logits w + hw over my 16 hidden units ----
    float w[NB * NB], hw[NB * NB];
    #pragma unroll
    for (int q = 0; q < NB * NB; ++q) { w[q] = 0.f; hw[q] = 0.f; }

    #pragma unroll 1
    for (int c = 0; c < 2; ++c) {
        #pragma unroll
        for (int hp = 0; hp < 8; ++hp) {
            const int h = par * 16 + c * 8 + hp;      // 2 distinct per wave -> broadcast
            const float g2v = s_g2[tid * 17 + c * 8 + hp];
            const float w2v = s_w2s[h];
            const float b1h = s_b1[h];
            float a[NB], bb[NB];
            #pragma unroll
            for (int j = 0; j < NB; ++j) { a[j] = b1h; bb[j] = 0.f; }
            const float* w1r = &s_W1t[h * W1P];
            #pragma unroll
            for (int dc = 0; dc < 3; ++dc) {          // 4 d's per step, b128 LDS reads
                const float4 wt = *reinterpret_cast<const float4*>(w1r + dc * 4);
                const float4 wb = *reinterpret_cast<const float4*>(w1r + DD + dc * 4);
                const float wtl[4] = {wt.x, wt.y, wt.z, wt.w};
                const float wbl[4] = {wb.x, wb.y, wb.z, wb.w};
                #pragma unroll
                for (int d4 = 0; d4 < 4; ++d4) {
                    const int d = dc * 4 + d4;
                    #pragma unroll
                    for (int j = 0; j < NB; ++j) {
                        a[j]  += o[j*DD + d] * wtl[d4];
                        bb[j] += o[j*DD + d] * wbl[d4];
                    }
                }
            }
            #pragma unroll
            for (int j = 0; j < NB; ++j) {
                #pragma unroll
                for (int k = 0; k < NB; ++k) {
                    const float hv = fmaxf(a[j] + bb[k], 0.f);
                    w[j*NB + k]  += hv * g2v;
                    hw[j*NB + k] += hv * w2v;
                }
            }
        }
    }

    // ---- combine h-halves with the paired lane (no LDS, no barrier) ----
    #pragma unroll
    for (int q = 0; q < NB * NB; ++q) {
        w[q]  += __shfl_xor(w[q], 1);
        hw[q] += __shfl_xor(hw[q], 1);
    }

    // ---- softmax over 25 pairs (redundant in both lanes; identical) ----
    float m = w[0];
    #pragma unroll
    for (int q = 1; q < NB * NB; ++q) m = fmaxf(m, w[q]);
    float racc[NB], zacc[NB];
    float l = 0.f;
    #pragma unroll
    for (int j = 0; j < NB; ++j) {
        float r = 0.f, z = 0.f;
        #pragma unroll
        for (int k = 0; k < NB; ++k) {
            const float e = __expf(w[j*NB + k] - m);
            r += e;
            z += e * hw[j*NB + k];
        }
        racc[j] = r; zacc[j] = z; l += r;
    }

    if (valid && par == 0) {
        const float invl = 1.f / l;
        const float sb2 = s_sb2;
        float* zr = zbuf + (size_t)i * zstride + zoff;
        #pragma unroll
        for (int j = 0; j < NB; ++j)
            zr[j] = (zacc[j] + sb2 * racc[j]) * invl;
    }
}

// ---------------- kernel B: assemble output (proven R3 path) ----------------
__global__ __launch_bounds__(BLOCK) void assemble_kernel(
    const float* __restrict__ obs, const float* __restrict__ ghat,
    const float* __restrict__ zbuf, int zstride, int zoff,
    float* __restrict__ out, int B)
{
    __shared__ float s_obs[TILE * NB * DD];  // 3840 floats
    __shared__ float s_gh[TILE * EE];        // 4096 floats
    __shared__ float s_zh[TILE * NB];        // 320 floats

    const int tid = threadIdx.x;
    const int r0 = blockIdx.x * TILE;
    const int rows = (B - r0 < TILE) ? (B - r0) : TILE;

    for (int t = tid; t < rows * NB * DD; t += BLOCK)
        s_obs[t] = obs[(size_t)r0 * NB * DD + t];
    for (int t = tid; t < rows * EE; t += BLOCK)
        s_gh[t] = ghat[(size_t)r0 * EE + t];
    for (int t = tid; t < rows * NB; t += BLOCK) {
        const int row = t / NB, k = t - row * NB;
        s_zh[t] = zbuf[(size_t)(r0 + row) * zstride + zoff + k];
    }
    __syncthreads();

    const size_t base = (size_t)r0 * OUTW;
    for (int t = tid; t < rows * OUTW; t += BLOCK) {
        const int il = t / OUTW;
        const int r  = t - il * OUTW;
        const int j  = r / ROW;
        const int rr = r - j * ROW;
        float v;
        if (rr < DD)           v = s_obs[il * NB * DD + j * DD + rr];
        else if (rr < DD + EE) v = s_gh[il * EE + (rr - DD)];
        else                   v = s_zh[il * NB + (rr - (DD + EE))];
        out[base + t] = v;
    }
}

extern "C" void kernel_launch(void* const* d_in, const int* in_sizes, int n_in,
                              void* d_out, int out_size, void* d_ws, size_t ws_size,
                              hipStream_t stream) {
    const float* obs  = (const float*)d_in[0];
    const float* ghat = (const float*)d_in[1];
    const float* W1   = (const float*)d_in[2];
    const float* b1   = (const float*)d_in[3];
    const float* W2   = (const float*)d_in[4];
    const float* b2   = (const float*)d_in[5];
    float* out = (float*)d_out;

    const int B = in_sizes[0] / (NB * DD);

    // zhat scratch: d_ws if large enough, else stash in last 5 floats of each
    // output row (assemble reads its tile's stash before overwriting it).
    float* zbuf; int zstride, zoff;
    if (ws_size >= (size_t)B * NB * sizeof(float)) {
        zbuf = (float*)d_ws; zstride = NB;   zoff = 0;
    } else {
        zbuf = out;          zstride = OUTW; zoff = OUTW - NB;
    }

    const int gridA = (B + BPB - 1) / BPB;
    hipLaunchKernelGGL(zhat_kernel, dim3(gridA), dim3(BLOCK), 0, stream,
                       obs, ghat, W1, b1, W2, b2, zbuf, zstride, zoff, B);

    const int gridB = (B + TILE - 1) / TILE;
    hipLaunchKernelGGL(assemble_kernel, dim3(gridB), dim3(BLOCK), 0, stream,
                       obs, ghat, zbuf, zstride, zoff, out, B);
}